// Round 8
// baseline (968.153 us; speedup 1.0000x reference)
//
#include <hip/hip_runtime.h>
#include <hip/hip_cooperative_groups.h>
#include <cmath>

namespace cg = cooperative_groups;

// ---------------------------------------------------------------------------
// Problem constants (from reference)
// ---------------------------------------------------------------------------
constexpr int kNsh    = 9;      // (LMAX+1)^2, LMAX=2
constexpr int kF      = 64;
constexpr int kNrbf   = 20;
constexpr int kNAtoms = 1000;
constexpr int kNPairs = 10000;
constexpr float kCutoffF = 5.0f;
constexpr int kMaxNZ  = 200;
constexpr int kCp     = 12;         // channel dim padded (9 -> 12) for b128
constexpr int kXs     = kF * kCp;   // 768 floats per atom, internal layout
constexpr int kPY     = kF * kCp;   // 768 floats per pair, pairY [f][12]
constexpr int kPPB    = kNPairs / kNAtoms;  // 10 pairs per block (msg phase)

// ---------------------------------------------------------------------------
// Compile-time real Clebsch-Gordan table (mirrors the reference _real_cg)
// ---------------------------------------------------------------------------
struct CGSparse {
  int n;
  int c[kMaxNZ];
  int a[kMaxNZ];
  int b[kMaxNZ];
  float v[kMaxNZ];
};

constexpr double cfact(int n) {
  double r = 1.0;
  for (int i = 2; i <= n; i++) r *= (double)i;
  return r;
}
constexpr double cabs_(double x) { return x < 0 ? -x : x; }
constexpr double csqrt_(double x) {
  if (x <= 0.0) return 0.0;
  double g = x < 1.0 ? 1.0 : x;
  for (int i = 0; i < 60; i++) g = 0.5 * (g + x / g);
  return g;
}

constexpr double cg_cplx(int l1, int m1, int l2, int m2, int l3, int m3) {
  if (m3 != m1 + m2) return 0.0;
  int lo = l1 > l2 ? l1 - l2 : l2 - l1;
  if (l3 < lo || l3 > l1 + l2) return 0.0;
  double pre = csqrt_((2 * l3 + 1) * cfact(l3 + l1 - l2) * cfact(l3 - l1 + l2) *
                      cfact(l1 + l2 - l3) / cfact(l1 + l2 + l3 + 1));
  pre *= csqrt_(cfact(l3 + m3) * cfact(l3 - m3) * cfact(l1 - m1) *
                cfact(l1 + m1) * cfact(l2 - m2) * cfact(l2 + m2));
  double s = 0.0;
  for (int k = 0; k <= l1 + l2 - l3; k++) {
    int d0 = k, d1 = l1 + l2 - l3 - k, d2 = l1 - m1 - k;
    int d3 = l2 + m2 - k, d4 = l3 - l2 + m1 + k, d5 = l3 - l1 - m2 + k;
    if (d0 < 0 || d1 < 0 || d2 < 0 || d3 < 0 || d4 < 0 || d5 < 0) continue;
    double den = cfact(d0) * cfact(d1) * cfact(d2) * cfact(d3) * cfact(d4) * cfact(d5);
    s += ((k % 2) ? -1.0 : 1.0) / den;
  }
  return pre * s;
}

constexpr CGSparse build_cg() {
  CGSparse out{};
  int lidx[9] = {0, 1, 1, 1, 2, 2, 2, 2, 2};
  int midx[9] = {0, -1, 0, 1, -2, -1, 0, 1, 2};
  double Ur[9][9] = {};
  double Ui[9][9] = {};
  for (int l = 0; l <= 2; l++) {
    int base = l * l + l;
    Ur[base][base] = 1.0;
    for (int m = 1; m <= l; m++) {
      double s2 = 1.0 / csqrt_(2.0);
      double sgn = (m % 2) ? -1.0 : 1.0;
      Ur[base + m][base - m] = s2;
      Ur[base + m][base + m] = sgn * s2;
      Ui[base - m][base - m] = s2;
      Ui[base - m][base + m] = -sgn * s2;
    }
  }
  double cgr[9][9][9] = {};
  for (int i = 0; i < 9; i++)
    for (int j = 0; j < 9; j++)
      for (int k = 0; k < 9; k++) {
        double cv = cg_cplx(lidx[i], midx[i], lidx[j], midx[j], lidx[k], midx[k]);
        if (cv == 0.0) continue;
        for (int a2 = 0; a2 < 9; a2++) {
          if (Ur[a2][i] == 0.0 && Ui[a2][i] == 0.0) continue;
          for (int b2 = 0; b2 < 9; b2++) {
            if (Ur[b2][j] == 0.0 && Ui[b2][j] == 0.0) continue;
            for (int c2 = 0; c2 < 9; c2++) {
              if (Ur[c2][k] == 0.0 && Ui[c2][k] == 0.0) continue;
              double ar = Ur[a2][i], ai = Ui[a2][i];
              double br = Ur[b2][j], bi = Ui[b2][j];
              double cr = Ur[c2][k], ci = -Ui[c2][k];  // conj
              double pr = ar * br - ai * bi;
              double pi = ar * bi + ai * br;
              double rr = pr * cr - pi * ci;  // real part
              cgr[c2][a2][b2] += rr * cv;
            }
          }
        }
      }
  int n = 0;
  for (int c2 = 0; c2 < 9; c2++)
    for (int a2 = 0; a2 < 9; a2++)
      for (int b2 = 0; b2 < 9; b2++) {
        bool mask = ((lidx[a2] + lidx[b2]) % 2) == (lidx[c2] % 2);
        double v = mask ? cgr[c2][a2][b2] : 0.0;
        if (cabs_(v) > 1e-9) {
          out.c[n] = c2;
          out.a[n] = a2;
          out.b[n] = b2;
          out.v[n] = (float)v;
          n++;
        }
      }
  out.n = n;
  return out;
}

constexpr CGSparse CG = build_cg();
static_assert(CG.n > 0 && CG.n <= kMaxNZ, "CG table size out of range");

// ---------------------------------------------------------------------------
// msg_phase<T>: block handles pairs [blk*10, blk*10+10), wave wv takes
// every 4th. Per pair (R7's verified math): geometry, Y, radial, filter,
// CG product, store pairY[p][f][12]. T==0 also fills seg from idx_i.
// ---------------------------------------------------------------------------
template <int T>
__device__ __forceinline__ void msg_phase(
    int blk, int wv, int f, const float* __restrict__ rij,
    const int* __restrict__ idx_i, const int* __restrict__ idx_j,
    const int* __restrict__ Z, const float* __restrict__ emb,
    const float* __restrict__ Wft, const float* __restrict__ bft,
    const float* __restrict__ x_in, float* __restrict__ pairY,
    int* __restrict__ seg) {
  for (int p = blk * kPPB + wv; p < blk * kPPB + kPPB; p += 4) {
    if (T == 0) {
      if (f == 0) {
        const int hi = idx_i[p];
        const int lo = (p == 0) ? 0 : idx_i[p - 1] + 1;
        for (int a = lo; a <= hi; a++) seg[a] = p;
      }
      if (f == 1 && p == kNPairs - 1) {
        const int hi = idx_i[p];
        for (int a = hi + 1; a <= kNAtoms; a++) seg[a] = kNPairs;
      }
    }

    const float rx = rij[3 * p + 0], ry = rij[3 * p + 1], rz = rij[3 * p + 2];
    const float d = sqrtf(rx * rx + ry * ry + rz * rz);
    const float inv = 1.0f / d;
    const float ux = rx * inv, uy = ry * inv, uz = rz * inv;
    const float cut = (d < kCutoffF) ? 0.5f * (cosf(d * (float)(M_PI / 5.0)) + 1.0f) : 0.0f;

    const float c0 = 0.28209479177387814f;  // 0.5/sqrt(pi)
    const float c1 = 0.4886025119029199f;   // sqrt(3/(4pi))
    const float c2 = 1.0925484305920792f;   // 0.5*sqrt(15/pi)
    const float c3 = 0.31539156525252005f;  // 0.25*sqrt(5/pi)
    const float c4 = 0.5462742152960396f;   // 0.25*sqrt(15/pi)
    float Y[9];
    Y[0] = c0;
    Y[1] = c1 * uy;
    Y[2] = c1 * uz;
    Y[3] = c1 * ux;
    Y[4] = c2 * ux * uy;
    Y[5] = c2 * uy * uz;
    Y[6] = c3 * (3.0f * uz * uz - 1.0f);
    Y[7] = c2 * ux * uz;
    Y[8] = c4 * (ux * ux - uy * uy);

    const float width = kCutoffF / (kNrbf - 1);
    const float coef = -0.5f / (width * width);
    float rad[kNrbf];
    #pragma unroll
    for (int k = 0; k < kNrbf; k++) {
      float off = (kCutoffF * k) / (kNrbf - 1);
      float tt = d - off;
      rad[k] = expf(coef * tt * tt) * cut;
    }

    float Wl0 = bft[f] * cut, Wl1 = bft[64 + f] * cut, Wl2 = bft[128 + f] * cut;
    #pragma unroll 5
    for (int k = 0; k < kNrbf; k++) {
      Wl0 += rad[k] * Wft[k * 192 + f];
      Wl1 += rad[k] * Wft[k * 192 + 64 + f];
      Wl2 += rad[k] * Wft[k * 192 + 128 + f];
    }

    float YW[9];
    YW[0] = Y[0] * Wl0;
    YW[1] = Y[1] * Wl1;
    YW[2] = Y[2] * Wl1;
    YW[3] = Y[3] * Wl1;
    #pragma unroll
    for (int b = 4; b < 9; b++) YW[b] = Y[b] * Wl2;

    const int j = idx_j[p];

    float y[12];
    #pragma unroll
    for (int c = 0; c < 12; c++) y[c] = 0.f;
    if (T == 0) {
      float e = emb[Z[j] * kF + f];
      #pragma unroll
      for (int q = 0; q < CG.n; q++) {
        if (CG.a[q] == 0) y[CG.c[q]] += CG.v[q] * YW[CG.b[q]] * e;
      }
    } else {
      const float* xj = x_in + j * kXs + f * kCp;
      float xv[12];
      *(float4*)&xv[0] = *(const float4*)(xj + 0);
      *(float4*)&xv[4] = *(const float4*)(xj + 4);
      *(float4*)&xv[8] = *(const float4*)(xj + 8);
      #pragma unroll
      for (int q = 0; q < CG.n; q++) {
        y[CG.c[q]] += CG.v[q] * YW[CG.b[q]] * xv[CG.a[q]];
      }
    }

    float* dst = pairY + p * kPY + f * kCp;
    *(float4*)(dst + 0) = *(float4*)&y[0];
    *(float4*)(dst + 4) = *(float4*)&y[4];
    *(float4*)(dst + 8) = *(float4*)&y[8];
  }
}

// ---------------------------------------------------------------------------
// mm_phase: k-split matmul partial (R0-verified). Wave covers 16 k-slices
// of the 12c x 64f tile; W streamed in two 8-slice register stages.
// ---------------------------------------------------------------------------
__device__ __forceinline__ void mm_phase(const float* __restrict__ sIn,
                                         const float* __restrict__ W,
                                         float* __restrict__ sRw,
                                         int k0, int cgi, int fb) {
  if (cgi >= 3) return;
  const int c0 = cgi * 4;
  float acc[4][4];
  #pragma unroll
  for (int i = 0; i < 4; i++)
    #pragma unroll
    for (int j = 0; j < 4; j++) acc[i][j] = 0.f;
  #pragma unroll
  for (int half = 0; half < 2; half++) {
    float4 wr[8];
    #pragma unroll
    for (int kk = 0; kk < 8; kk++) {
      wr[kk] = *(const float4*)(W + (k0 + half * 8 + kk) * kF + fb);
    }
    #pragma unroll
    for (int kk = 0; kk < 8; kk++) {
      int k = k0 + half * 8 + kk;
      float4 av = *(const float4*)(sIn + k * kCp + c0);
      float4 wv = wr[kk];
      float a[4] = {av.x, av.y, av.z, av.w};
      float w[4] = {wv.x, wv.y, wv.z, wv.w};
      #pragma unroll
      for (int i = 0; i < 4; i++)
        #pragma unroll
        for (int j = 0; j < 4; j++) acc[i][j] += a[i] * w[j];
    }
  }
  #pragma unroll
  for (int j = 0; j < 4; j++) {
    float4 v = {acc[0][j], acc[1][j], acc[2][j], acc[3][j]};
    *(float4*)(sRw + (fb + j) * kCp + c0) = v;
  }
}

// ---------------------------------------------------------------------------
// upd_phase<T>: 4-wave update for atom = blk (R0/R4-verified structure).
// Message replaced by segmented pairY reduction (idx_i sorted -> contiguous).
// T==0: residual emb ch0, write internal [f][12]. T==1: residual x_in,
// write standard [c][f].
// ---------------------------------------------------------------------------
template <int T>
__device__ void upd_phase(
    int atom, int tid, const int* __restrict__ Z,
    const float* __restrict__ emb, const float* __restrict__ W1,
    const float* __restrict__ W2, const float* __restrict__ W3,
    const float* __restrict__ Wg, const float* __restrict__ bg,
    const float* __restrict__ pairY, const int* __restrict__ seg,
    const float* __restrict__ x_in, float* __restrict__ x_out,
    float* __restrict__ sA, float (*__restrict__ sR)[kF * kCp],
    float (*__restrict__ sGp)[192]) {
  const int wv = tid >> 6;
  const int lane = tid & 63;
  const int cgi = lane >> 4;
  const int fb = (lane & 15) * 4;
  const int k0 = wv * 16;

  // ---- segmented reduction of pairY (bulk float4 streams) ----
  {
    const int s0 = seg[atom], s1 = seg[atom + 1];
    float y[12];
    #pragma unroll
    for (int c = 0; c < 12; c++) y[c] = 0.f;
    for (int p0 = s0 + wv; p0 < s1; p0 += 4) {
      const float* py = pairY + p0 * kPY + lane * kCp;
      float4 a = *(const float4*)(py + 0);
      float4 b = *(const float4*)(py + 4);
      float4 c4 = *(const float4*)(py + 8);
      y[0] += a.x;  y[1] += a.y;  y[2] += a.z;  y[3] += a.w;
      y[4] += b.x;  y[5] += b.y;  y[6] += b.z;  y[7] += b.w;
      y[8] += c4.x; y[9] += c4.y; y[10] += c4.z; y[11] += c4.w;
    }
    float4* r4 = (float4*)(sR[wv] + lane * kCp);
    r4[0] = *(float4*)&y[0];
    r4[1] = *(float4*)&y[4];
    r4[2] = *(float4*)&y[8];
  }
  __syncthreads();  // B1
  if (tid < 192) {
    const float4* r0 = (const float4*)sR[0];
    const float4* r1 = (const float4*)sR[1];
    const float4* r2 = (const float4*)sR[2];
    const float4* r3 = (const float4*)sR[3];
    float4 a = r0[tid], b = r1[tid], c = r2[tid], d = r3[tid];
    float4 s = {a.x + b.x + c.x + d.x, a.y + b.y + c.y + d.y,
                a.z + b.z + c.z + d.z, a.w + b.w + c.w + d.w};
    ((float4*)sA)[tid] = s;
  }
  __syncthreads();  // B2

  mm_phase(sA, W1, sR[wv], k0, cgi, fb);
  __syncthreads();  // B3

  if (wv == 0) {
    float dxv[12], ddx[12];
    {
      const float4* sa = (const float4*)(sA + lane * kCp);
      *(float4*)&dxv[0] = sa[0];
      *(float4*)&dxv[4] = sa[1];
      *(float4*)&dxv[8] = sa[2];
    }
    #pragma unroll
    for (int c = 0; c < 12; c++) {
      ddx[c] = sR[0][lane * kCp + c] + sR[1][lane * kCp + c] +
               sR[2][lane * kCp + c] + sR[3][lane * kCp + c];
    }
    float t2[12];
    #pragma unroll
    for (int c = 0; c < 9; c++) t2[c] = dxv[c];
    t2[9] = 0.f; t2[10] = 0.f; t2[11] = 0.f;
    #pragma unroll
    for (int q = 0; q < CG.n; q++) {
      t2[CG.c[q]] += CG.v[q] * dxv[CG.a[q]] * ddx[CG.b[q]];
    }
    float4* sa = (float4*)(sA + lane * kCp);
    sa[0] = *(float4*)&t2[0];
    sa[1] = *(float4*)&t2[4];
    sa[2] = *(float4*)&t2[8];
  }
  __syncthreads();  // B4

  mm_phase(sA, W2, sR[wv], k0, cgi, fb);
  __syncthreads();  // B5

  {
    float g0 = 0.f, g1 = 0.f, g2 = 0.f;
    #pragma unroll 4
    for (int kk = 0; kk < 16; kk++) {
      int k = k0 + kk;
      float a = sR[0][k * kCp] + sR[1][k * kCp] + sR[2][k * kCp] + sR[3][k * kCp];
      g0 += a * Wg[k * 192 + lane];
      g1 += a * Wg[k * 192 + 64 + lane];
      g2 += a * Wg[k * 192 + 128 + lane];
    }
    sGp[wv][lane] = g0;
    sGp[wv][64 + lane] = g1;
    sGp[wv][128 + lane] = g2;
  }
  __syncthreads();  // B6

  if (wv == 0) {
    float dx2v[12];
    #pragma unroll
    for (int c = 0; c < 12; c++) {
      dx2v[c] = sR[0][lane * kCp + c] + sR[1][lane * kCp + c] +
                sR[2][lane * kCp + c] + sR[3][lane * kCp + c];
    }
    float g0 = bg[lane] + sGp[0][lane] + sGp[1][lane] + sGp[2][lane] + sGp[3][lane];
    float g1 = bg[64 + lane] + sGp[0][64 + lane] + sGp[1][64 + lane] +
               sGp[2][64 + lane] + sGp[3][64 + lane];
    float g2 = bg[128 + lane] + sGp[0][128 + lane] + sGp[1][128 + lane] +
               sGp[2][128 + lane] + sGp[3][128 + lane];
    g0 = 1.f / (1.f + expf(-g0));
    g1 = 1.f / (1.f + expf(-g1));
    g2 = 1.f / (1.f + expf(-g2));
    float dx3[12];
    dx3[0] = dx2v[0] * g0;
    dx3[1] = dx2v[1] * g1;
    dx3[2] = dx2v[2] * g1;
    dx3[3] = dx2v[3] * g1;
    #pragma unroll
    for (int c = 4; c < 9; c++) dx3[c] = dx2v[c] * g2;
    dx3[9] = 0.f; dx3[10] = 0.f; dx3[11] = 0.f;
    float4* sa = (float4*)(sA + lane * kCp);
    sa[0] = *(float4*)&dx3[0];
    sa[1] = *(float4*)&dx3[4];
    sa[2] = *(float4*)&dx3[8];
  }
  __syncthreads();  // B7

  mm_phase(sA, W3, sR[wv], k0, cgi, fb);
  __syncthreads();  // B8

  if (T == 0) {
    if (tid < 192) {
      const int f = tid / 3, r = tid % 3;
      const float4* r0 = (const float4*)sR[0];
      const float4* r1 = (const float4*)sR[1];
      const float4* r2 = (const float4*)sR[2];
      const float4* r3 = (const float4*)sR[3];
      float4 a = r0[tid], b = r1[tid], c = r2[tid], d = r3[tid];
      float4 s = {a.x + b.x + c.x + d.x, a.y + b.y + c.y + d.y,
                  a.z + b.z + c.z + d.z, a.w + b.w + c.w + d.w};
      if (r == 0) s.x += emb[Z[atom] * kF + f];
      *(float4*)(x_out + atom * kXs + tid * 4) = s;
    }
  } else {
    if (tid < 192) {
      const float4* r0 = (const float4*)sR[0];
      const float4* r1 = (const float4*)sR[1];
      const float4* r2 = (const float4*)sR[2];
      const float4* r3 = (const float4*)sR[3];
      float4 a = r0[tid], b = r1[tid], c = r2[tid], d = r3[tid];
      float4 xi = *(const float4*)(x_in + atom * kXs + tid * 4);
      float4 s = {a.x + b.x + c.x + d.x + xi.x, a.y + b.y + c.y + d.y + xi.y,
                  a.z + b.z + c.z + d.z + xi.z, a.w + b.w + c.w + d.w + xi.w};
      ((float4*)sA)[tid] = s;
    }
    __syncthreads();  // B9
    #pragma unroll
    for (int r = 0; r < 3; r++) {
      int i = r * 256 + tid;
      if (i < kNsh * kF) {
        int c = i >> 6, f = i & 63;
        x_out[atom * (kNsh * kF) + i] = sA[f * kCp + c];
      }
    }
  }
}

// ---------------------------------------------------------------------------
// k_so3: mode==-1 -> full cooperative run (3 grid syncs); mode==0..3 ->
// single phase (fallback path, kernel boundaries provide coherence).
// LDS 18.3 KB, VGPR capped by __launch_bounds__(256,4) -> 4 blocks/CU
// guaranteed -> 1024 >= 1000 co-resident blocks for the cooperative launch.
// ---------------------------------------------------------------------------
__global__ __launch_bounds__(256, 4) void k_so3(
    int mode, const float* __restrict__ rij, const int* __restrict__ idx_i,
    const int* __restrict__ idx_j, const int* __restrict__ Z,
    const float* __restrict__ emb, const float* __restrict__ Wf,
    const float* __restrict__ bf, const float* __restrict__ W1,
    const float* __restrict__ W2, const float* __restrict__ W3,
    const float* __restrict__ Wg, const float* __restrict__ bg,
    float* __restrict__ x1, float* __restrict__ pairY,
    int* __restrict__ seg, float* __restrict__ out) {
  const int blk = blockIdx.x;
  const int tid = threadIdx.x;
  const int wv = tid >> 6;
  const int lane = tid & 63;

  __shared__ __align__(16) float sA[kF * kCp];      // 3 KB
  __shared__ __align__(16) float sR[4][kF * kCp];   // 12 KB
  __shared__ __align__(16) float sGp[4][192];       // 3 KB

  if (mode == -1) {
    msg_phase<0>(blk, wv, lane, rij, idx_i, idx_j, Z, emb, Wf, bf,
                 (const float*)nullptr, pairY, seg);
    __threadfence();
    cg::this_grid().sync();
    upd_phase<0>(blk, tid, Z, emb, W1, W2, W3, Wg, bg, pairY, seg,
                 (const float*)nullptr, x1, sA, sR, sGp);
    __threadfence();
    cg::this_grid().sync();
    msg_phase<1>(blk, wv, lane, rij, idx_i, idx_j, Z, emb,
                 Wf + kNrbf * 192, bf + 192, x1, pairY, seg);
    __threadfence();
    cg::this_grid().sync();
    upd_phase<1>(blk, tid, Z, emb, W1 + kF * kF, W2 + kF * kF, W3 + kF * kF,
                 Wg + kF * 192, bg + 192, pairY, seg, x1, out, sA, sR, sGp);
  } else if (mode == 0) {
    msg_phase<0>(blk, wv, lane, rij, idx_i, idx_j, Z, emb, Wf, bf,
                 (const float*)nullptr, pairY, seg);
  } else if (mode == 1) {
    upd_phase<0>(blk, tid, Z, emb, W1, W2, W3, Wg, bg, pairY, seg,
                 (const float*)nullptr, x1, sA, sR, sGp);
  } else if (mode == 2) {
    msg_phase<1>(blk, wv, lane, rij, idx_i, idx_j, Z, emb,
                 Wf + kNrbf * 192, bf + 192, x1, pairY, seg);
  } else {
    upd_phase<1>(blk, tid, Z, emb, W1 + kF * kF, W2 + kF * kF, W3 + kF * kF,
                 Wg + kF * 192, bg + 192, pairY, seg, x1, out, sA, sR, sGp);
  }
}

// ---------------------------------------------------------------------------
// Launch: try ONE cooperative dispatch; on any error fall back to 4 normal
// mode-sliced dispatches (kernel boundaries = coherence).
// ---------------------------------------------------------------------------
extern "C" void kernel_launch(void* const* d_in, const int* in_sizes, int n_in,
                              void* d_out, int out_size, void* d_ws, size_t ws_size,
                              hipStream_t stream) {
  const int* Z        = (const int*)d_in[0];
  const float* rij    = (const float*)d_in[1];
  const int* idx_i    = (const int*)d_in[2];
  const int* idx_j    = (const int*)d_in[3];
  const float* emb    = (const float*)d_in[4];
  const float* Wf     = (const float*)d_in[5];
  const float* bf     = (const float*)d_in[6];
  const float* W1     = (const float*)d_in[7];
  const float* W2     = (const float*)d_in[8];
  const float* W3     = (const float*)d_in[9];
  const float* Wg     = (const float*)d_in[10];
  const float* bg     = (const float*)d_in[11];
  float* out = (float*)d_out;

  float* x1    = (float*)d_ws;                    // 768,000 floats (internal)
  float* pairY = x1 + kNAtoms * kXs;              // 7,680,000 floats (30.7 MB)
  int*   seg   = (int*)(pairY + kNPairs * kPY);   // 1001 ints

  int mode = -1;
  void* args[] = {(void*)&mode, (void*)&rij, (void*)&idx_i, (void*)&idx_j,
                  (void*)&Z, (void*)&emb, (void*)&Wf, (void*)&bf,
                  (void*)&W1, (void*)&W2, (void*)&W3, (void*)&Wg,
                  (void*)&bg, (void*)&x1, (void*)&pairY, (void*)&seg,
                  (void*)&out};
  hipError_t err = hipLaunchCooperativeKernel(
      (const void*)k_so3, dim3(kNAtoms), dim3(256), args, 0, stream);

  if (err != hipSuccess) {
    (void)hipGetLastError();  // clear sticky error, then fall back
    k_so3<<<kNAtoms, 256, 0, stream>>>(0, rij, idx_i, idx_j, Z, emb, Wf, bf,
                                       W1, W2, W3, Wg, bg, x1, pairY, seg, out);
    k_so3<<<kNAtoms, 256, 0, stream>>>(1, rij, idx_i, idx_j, Z, emb, Wf, bf,
                                       W1, W2, W3, Wg, bg, x1, pairY, seg, out);
    k_so3<<<kNAtoms, 256, 0, stream>>>(2, rij, idx_i, idx_j, Z, emb, Wf, bf,
                                       W1, W2, W3, Wg, bg, x1, pairY, seg, out);
    k_so3<<<kNAtoms, 256, 0, stream>>>(3, rij, idx_i, idx_j, Z, emb, Wf, bf,
                                       W1, W2, W3, Wg, bg, x1, pairY, seg, out);
  }
}